// Round 7
// baseline (1322.052 us; speedup 1.0000x reference)
//
#include <hip/hip_runtime.h>
#include <hip/hip_cooperative_groups.h>
#include <cmath>
#include <cstdint>

namespace cg = cooperative_groups;

// B=64, T=64, W=20, D=1024, K=4, STRIDE=4 ; conv lengths 64->16->4->1 ; T_total=21
// VCb is STACKED: rows [0,1024)=conv0-level (j=r>>4,t=r&15), [1024,1280)=conv1-level
// (j=(r-1024)>>2, t=16+((r-1024)&3)), [1280,1344)=conv2-level (j=r-1280, t=20).

typedef __bf16 bf16_t;
typedef bf16_t bf16x8 __attribute__((ext_vector_type(8)));
typedef bf16_t bf16x4 __attribute__((ext_vector_type(4)));
typedef bf16_t bf16x2 __attribute__((ext_vector_type(2)));
typedef float  f32x4  __attribute__((ext_vector_type(4)));

#define CP0_SL   1048576
#define CP1_SL   262144
#define CP2_SL   65536

#define MFMA16(a,b,c) __builtin_amdgcn_mfma_f32_16x16x32_bf16(a, b, c, 0, 0, 0)

__device__ __forceinline__ void gload_lds16(const void* g, void* l) {
    __builtin_amdgcn_global_load_lds(
        (const __attribute__((address_space(1))) void*)g,
        (__attribute__((address_space(3))) void*)l, 16, 0, 0);
}

// swizzle for BK=64 rows (8 chunks):   phys chunk = c ^ (r&7),  row stride 64 bf16
__device__ __forceinline__ int swz(int r, int c)    { return (r * 8  + (c ^ (r & 7)))  * 8; }
// swizzle for BK=128 rows (16 chunks): phys chunk = c ^ (r&15), row stride 128 bf16
__device__ __forceinline__ int swz128(int r, int c) { return (r * 16 + (c ^ (r & 15))) * 8; }

// ---------------- LDS-staged (i,k)->(k,i) weight transpose, 4 o-rows/block ----
__device__ __forceinline__ void wtrans4(const float* __restrict__ w,
                                        bf16_t* __restrict__ wt,
                                        int o0, int tid, bf16_t* lds /*16384*/)
{
    #pragma unroll
    for (int oo = 0; oo < 4; oo++) {
        const float* src = w + ((size_t)(o0 + oo) << 12);
        #pragma unroll
        for (int q = 0; q < 2; q++) {
            f32x4 va = *(const f32x4*)(src + tid * 16 + q * 8);
            f32x4 vb = *(const f32x4*)(src + tid * 16 + q * 8 + 4);
            int ib = tid * 4 + 2 * q;
            #pragma unroll
            for (int k = 0; k < 4; k++) {
                bf16x2 p2 = { (bf16_t)va[k], (bf16_t)vb[k] };
                *(bf16x2*)(lds + oo * 4096 + k * 1024 + ib) = p2;
            }
        }
    }
    __syncthreads();
    #pragma unroll
    for (int oo = 0; oo < 4; oo++) {
        bf16x8 v0 = *(bf16x8*)(lds + oo * 4096 + tid * 16);
        bf16x8 v1 = *(bf16x8*)(lds + oo * 4096 + tid * 16 + 8);
        bf16_t* dst = wt + ((size_t)(o0 + oo) << 12) + tid * 16;
        *(bf16x8*)dst       = v0;
        *(bf16x8*)(dst + 8) = v1;
    }
}

// ---------------- wide f32 -> bf16 cast, 8 elems/thread -----------------------
__device__ __forceinline__ void cast8(const float* __restrict__ s,
                                      bf16_t* __restrict__ d, int idx8)
{
    f32x4 a = *(const f32x4*)(s + (size_t)idx8 * 8);
    f32x4 b = *(const f32x4*)(s + (size_t)idx8 * 8 + 4);
    bf16x8 o;
    #pragma unroll
    for (int e = 0; e < 4; e++) { o[e] = (bf16_t)a[e]; o[4 + e] = (bf16_t)b[e]; }
    *(bf16x8*)(d + (size_t)idx8 * 8) = o;
}

// -------- 64x64 bf16 MFMA NT tile, BK=128, double-buffered (64KB LDS) ---------
__device__ __forceinline__ void gemm64(
    const bf16_t* __restrict__ A, const bf16_t* __restrict__ B,
    int Nc, int K, int m0A, int n0B, int k0, int nIt, int m0C, int n0C,
    bf16_t* sA, bf16_t* sB,            // each 2 x 8192 bf16
    float* __restrict__ Cf, const float* __restrict__ bias, bf16_t* __restrict__ Dbf,
    int relu)
{
    const int tid  = threadIdx.x;
    const int lane = tid & 63, wave = tid >> 6;
    const bf16_t* AgP[4]; const bf16_t* BgP[4];
    #pragma unroll
    for (int g = 0; g < 4; g++) {
        int q = g * 256 + tid, row = q >> 4, pcc = q & 15, lcc = pcc ^ (row & 15);
        AgP[g] = A + (size_t)(m0A + row) * K + k0 + lcc * 8;
        BgP[g] = B + (size_t)(n0B + row) * K + k0 + lcc * 8;
    }
    const int wr = (wave >> 1) * 32, wc = (wave & 1) * 32;
    const int fm = lane & 15, cb = lane >> 4;
    int offA[4][2], offB[4][2];
    #pragma unroll
    for (int h = 0; h < 4; h++) {
        offA[h][0] = swz128(wr +      fm, cb + h * 4);
        offA[h][1] = swz128(wr + 16 + fm, cb + h * 4);
        offB[h][0] = swz128(wc +      fm, cb + h * 4);
        offB[h][1] = swz128(wc + 16 + fm, cb + h * 4);
    }
    f32x4 acc[2][2];
    #pragma unroll
    for (int a = 0; a < 2; a++)
        #pragma unroll
        for (int b = 0; b < 2; b++) acc[a][b] = (f32x4){0.f, 0.f, 0.f, 0.f};

    #pragma unroll
    for (int g = 0; g < 4; g++) {
        gload_lds16(AgP[g], sA + (g * 256 + tid) * 8);
        gload_lds16(BgP[g], sB + (g * 256 + tid) * 8);
    }
    for (int it = 0; it < nIt; ++it) {
        const int buf = it & 1;
        const bf16_t* cA = sA + buf * 8192;
        const bf16_t* cB = sB + buf * 8192;
        __syncthreads();
        if (it + 1 < nIt) {
            bf16_t* dA = sA + (buf ^ 1) * 8192;
            bf16_t* dB = sB + (buf ^ 1) * 8192;
            #pragma unroll
            for (int g = 0; g < 4; g++) {
                gload_lds16(AgP[g] + (it + 1) * 128, dA + (g * 256 + tid) * 8);
                gload_lds16(BgP[g] + (it + 1) * 128, dB + (g * 256 + tid) * 8);
            }
        }
        #pragma unroll
        for (int h = 0; h < 4; h++) {
            bf16x8 a0 = *(const bf16x8*)&cA[offA[h][0]];
            bf16x8 a1 = *(const bf16x8*)&cA[offA[h][1]];
            bf16x8 b0 = *(const bf16x8*)&cB[offB[h][0]];
            bf16x8 b1 = *(const bf16x8*)&cB[offB[h][1]];
            acc[0][0] = MFMA16(a0, b0, acc[0][0]);
            acc[0][1] = MFMA16(a0, b1, acc[0][1]);
            acc[1][0] = MFMA16(a1, b0, acc[1][0]);
            acc[1][1] = MFMA16(a1, b1, acc[1][1]);
        }
    }
    // C/D layout: col = lane&15, row = (lane>>4)*4 + reg   [verified m89/m91]
    #pragma unroll
    for (int im = 0; im < 2; im++)
        #pragma unroll
        for (int rr = 0; rr < 4; rr++) {
            int gm = m0C + wr + im * 16 + cb * 4 + rr;
            #pragma unroll
            for (int in_ = 0; in_ < 2; in_++) {
                int cg = n0C + wc + in_ * 16 + fm;
                float v = acc[im][in_][rr];
                if (bias) v += bias[cg];
                if (relu) v = fmaxf(v, 0.f);
                if (Dbf) Dbf[(size_t)gm * Nc + cg] = (bf16_t)v;
                else     Cf[(size_t)gm * Nc + cg] = v;
            }
        }
}

// ---------------- wave-per-row L2 norm of a VCb row ---------------------------
__device__ __forceinline__ void rownorm_row(const bf16_t* __restrict__ VCb,
                                            float* __restrict__ VN, int r, int tid)
{
    const int lane = tid & 63;
    const bf16_t* x = VCb + ((size_t)r << 10) + lane * 16;
    bf16x8 v0 = *(const bf16x8*)x, v1 = *(const bf16x8*)(x + 8);
    float s = 0.f;
    #pragma unroll
    for (int e = 0; e < 8; e++) {
        float a = (float)v0[e], b = (float)v1[e];
        s += a * a + b * b;
    }
    #pragma unroll
    for (int o = 32; o; o >>= 1) s += __shfl_xor(s, o, 64);
    if (lane == 0) VN[r] = sqrtf(s);
}

// -- per-(i, stacked-col) sim: atomic SC accumulate + direct posmap write ------
__device__ __forceinline__ void sim_compute(
    int i, int c, const float* __restrict__ CPat, const float* __restrict__ VN,
    const float* Gs, const float* msk,
    float* __restrict__ SC, float* __restrict__ out)
{
    float s[20], p[20];
    float mx = -1e30f;
    #pragma unroll
    for (int w = 0; w < 20; w++) {
        s[w] = CPat[(size_t)(i * 20 + w) * 1344 + c];
        if (msk[w] != 0.f) mx = fmaxf(mx, s[w]);
    }
    float denom = 0.f, num = 0.f;
    #pragma unroll
    for (int w = 0; w < 20; w++) {
        p[w] = (msk[w] != 0.f) ? __expf(s[w] - mx) : 0.f;
        denom += p[w];
        num   += p[w] * s[w];
    }
    float quad = 0.f;
    #pragma unroll
    for (int w = 0; w < 20; w++) {
        float cc = 0.f;
        #pragma unroll
        for (int w2 = 0; w2 < 20; w2++) cc += Gs[w * 20 + w2] * p[w2];
        quad += p[w] * cc;
    }
    float dot = num / denom;
    float vsn = sqrtf(fmaxf(quad, 0.f)) / denom;
    float sim = dot / (fmaxf(VN[c], 1e-8f) * fmaxf(vsn, 1e-8f));
    int j, t;
    if (c < 1024)      { j = c >> 4;          t = c & 15; }
    else if (c < 1280) { j = (c - 1024) >> 2; t = 16 + ((c - 1024) & 3); }
    else               { j = c - 1280;        t = 20; }
    atomicAdd(SC + i * 64 + j, sim * (1.0f / 21.0f));
    if (i == j) out[1 + i * 21 + t] = sim;
}

// ---------------- gram dot for one (i, w, w2) pair (wave-wide) ----------------
__device__ __forceinline__ void gram_pair(const bf16_t* __restrict__ Wordsb,
                                          float* __restrict__ GR, int p, int lane)
{
    int i = p / 400, pr = p % 400, w = pr / 20, w2 = pr % 20;
    const bf16_t* a = Wordsb + (((size_t)i * 20 + w)  << 10) + lane * 16;
    const bf16_t* b = Wordsb + (((size_t)i * 20 + w2) << 10) + lane * 16;
    bf16x8 a0 = *(const bf16x8*)a, a1 = *(const bf16x8*)(a + 8);
    bf16x8 b0 = *(const bf16x8*)b, b1 = *(const bf16x8*)(b + 8);
    float s = 0.f;
    #pragma unroll
    for (int e = 0; e < 8; e++)
        s += (float)a0[e] * (float)b0[e] + (float)a1[e] * (float)b1[e];
    #pragma unroll
    for (int o = 32; o; o >>= 1) s += __shfl_xor(s, o, 64);
    if (lane == 0) GR[(size_t)i * 400 + pr] = s;
}

// =============================================================================
//                     COOPERATIVE MEGA-KERNEL (512 blocks)
// =============================================================================
__global__ __launch_bounds__(256, 2) void mega_kernel(
    const float* __restrict__ video, const float* __restrict__ words,
    const int* __restrict__ wmask, const float* __restrict__ sent,
    const float* __restrict__ c0w, const float* __restrict__ c0b,
    const float* __restrict__ c1w, const float* __restrict__ c1b,
    const float* __restrict__ c2w, const float* __restrict__ c2b,
    const float* __restrict__ c1dw, const float* __restrict__ c1db,
    const float* __restrict__ fcw, const float* __restrict__ fcb,
    bf16_t* __restrict__ WT0, bf16_t* __restrict__ WT1, bf16_t* __restrict__ WT2,
    bf16_t* __restrict__ Vb, bf16_t* __restrict__ Wordsb,
    bf16_t* __restrict__ C1b, bf16_t* __restrict__ Fb,
    bf16_t* __restrict__ Astack, bf16_t* __restrict__ A2b, bf16_t* __restrict__ A3b,
    bf16_t* __restrict__ VCb,
    float* __restrict__ CP0, float* __restrict__ CP1, float* __restrict__ CP2,
    float* __restrict__ CPat, float* __restrict__ VN, float* __restrict__ GR,
    float* __restrict__ SC, float* __restrict__ GV, float* __restrict__ GS,
    float* __restrict__ out)
{
    cg::grid_group grid = cg::this_grid();
    __shared__ __align__(16) bf16_t smem[32768];   // 64KB
    bf16_t* sA = smem; bf16_t* sB = smem + 16384;
    const int bid = blockIdx.x, tid = threadIdx.x;
    const int wave = tid >> 6, lane = tid & 63;

    // ---------------- P0: ALL prep (transposes, casts, SC zero) ---------------
    for (int u = bid; u < 4484; u += 512) {
        if (u < 256)       wtrans4(c0w, WT0, u * 4, tid, smem);
        else if (u < 512)  wtrans4(c1w, WT1, (u - 256) * 4, tid, smem);
        else if (u < 768)  wtrans4(c2w, WT2, (u - 512) * 4, tid, smem);
        else if (u < 2816) cast8(video, Vb, (u - 768) * 256 + tid);
        else if (u < 3456) cast8(words, Wordsb, (u - 2816) * 256 + tid);
        else if (u < 3968) cast8(c1dw, C1b, (u - 3456) * 256 + tid);
        else if (u < 4480) cast8(fcw, Fb, (u - 3968) * 256 + tid);
        else { int idx = (u - 4480) * 1024 + tid * 4;
               *(f32x4*)(SC + idx) = (f32x4){0.f, 0.f, 0.f, 0.f}; }
        __syncthreads();
    }
    __threadfence(); grid.sync();

    // ---------------- P1: conv0 128x128 tile, splitK x8 (512 blocks) ----------
    {
        const int z = bid >> 6, rem = bid & 63, xt = rem & 7, yt = rem >> 3;
        const int m0 = xt * 128, n0 = yt * 128, k0 = z * 512;
        const int sr = tid >> 3, pc = tid & 7, lc = pc ^ (sr & 7);
        const bf16_t* Ag = Vb  + (size_t)(m0 + sr) * 4096 + k0 + lc * 8;
        const bf16_t* Bg = WT0 + (size_t)(n0 + sr) * 4096 + k0 + lc * 8;
        const size_t rowskip = (size_t)32 * 4096;
        const int wrow = (wave >> 1) * 64, wcol = (wave & 1) * 64;
        const int fm = lane & 15, cb = lane >> 4;
        int offA[2][4], offB[2][4];
        #pragma unroll
        for (int h = 0; h < 2; h++)
            #pragma unroll
            for (int m = 0; m < 4; m++) {
                offA[h][m] = swz(wrow + m * 16 + fm, cb + h * 4);
                offB[h][m] = swz(wcol + m * 16 + fm, cb + h * 4);
            }
        f32x4 acc[4][4];
        #pragma unroll
        for (int m = 0; m < 4; m++)
            #pragma unroll
            for (int n = 0; n < 4; n++) acc[m][n] = (f32x4){0.f, 0.f, 0.f, 0.f};

        #pragma unroll
        for (int g = 0; g < 4; g++) {
            gload_lds16(Ag + g * rowskip, &sA[tid * 8 + g * 2048]);
            gload_lds16(Bg + g * rowskip, &sB[tid * 8 + g * 2048]);
        }
        for (int it = 0; it < 8; ++it) {
            const int buf = it & 1;
            __syncthreads();
            if (it < 7) {
                const bf16_t* a = Ag + (it + 1) * 64;
                const bf16_t* b = Bg + (it + 1) * 64;
                #pragma unroll
                for (int g = 0; g < 4; g++) {
                    gload_lds16(a + g * rowskip, &sA[(buf ^ 1) * 8192 + tid * 8 + g * 2048]);
                    gload_lds16(b + g * rowskip, &sB[(buf ^ 1) * 8192 + tid * 8 + g * 2048]);
                }
            }
            #pragma unroll
            for (int h = 0; h < 2; h++) {
                bf16x8 av[4], bv[4];
                #pragma unroll
                for (int m = 0; m < 4; m++) {
                    av[m] = *(const bf16x8*)&sA[buf * 8192 + offA[h][m]];
                    bv[m] = *(const bf16x8*)&sB[buf * 8192 + offB[h][m]];
                }
                #pragma unroll
                for (int m = 0; m < 4; m++)
                    #pragma unroll
                    for (int n = 0; n < 4; n++)
                        acc[m][n] = MFMA16(av[m], bv[n], acc[m][n]);
            }
        }
        float* Cz = CP0 + (size_t)z * CP0_SL;
        #pragma unroll
        for (int m = 0; m < 4; m++)
            #pragma unroll
            for (int rr = 0; rr < 4; rr++) {
                int gm = m0 + wrow + m * 16 + cb * 4 + rr;
                #pragma unroll
                for (int n = 0; n < 4; n++) {
                    int cg = n0 + wcol + n * 16 + fm;
                    Cz[(size_t)gm * 1024 + cg] = acc[m][n][rr];
                }
            }
    }
    __threadfence(); grid.sync();

    // ---------------- P2: conv0 epilogue (8 slices) + gram --------------------
    {
        int idx8 = bid * 256 + tid;          // 512 units cover 131072 idx8
        size_t base = (size_t)idx8 * 8;
        int nb = (int)(base & 1023);
        f32x4 s0 = *(const f32x4*)(c0b + nb);
        f32x4 s1 = *(const f32x4*)(c0b + nb + 4);
        #pragma unroll
        for (int z = 0; z < 8; z++) {
            const float* p = CP0 + (size_t)z * CP0_SL + base;
            s0 += *(const f32x4*)p;
            s1 += *(const f32x4*)(p + 4);
        }
        bf16x8 o;
        #pragma unroll
        for (int e = 0; e < 4; e++) {
            o[e]     = (bf16_t)fmaxf(s0[e], 0.f);
            o[4 + e] = (bf16_t)fmaxf(s1[e], 0.f);
        }
        *(bf16x8*)(Astack + base) = o;
    }
    for (int p = bid * 4 + wave; p < 25600; p += 2048)
        gram_pair(Wordsb, GR, p, lane);
    __threadfence(); grid.sync();

    // ---------------- P3: conv1 splitK x4 -> CP1  ||  c1d0 -> VCb[0..1024) ----
    if (bid < 256) {
        int z = bid >> 6, rem = bid & 63, xt = rem & 3, yt = rem >> 2;
        gemm64(Astack, WT1, 1024, 4096, xt * 64, yt * 64, z * 1024, 8,
               xt * 64, yt * 64, sA, sB, CP1 + (size_t)z * CP1_SL, nullptr, nullptr, 0);
    } else {
        int b2 = bid - 256;
        int xt = b2 & 15, yt = b2 >> 4;
        gemm64(Astack, C1b, 1024, 1024, xt * 64, yt * 64, 0, 8,
               xt * 64, yt * 64, sA, sB, nullptr, c1db, VCb, 0);
    }
    __threadfence(); grid.sync();

    // --------- P4: attn0 (cols<1024)  ||  conv1-epi -> A2b  ||  rownorm0 ------
    if (bid < 320) {
        int xt = bid % 20, yt = bid / 20;
        gemm64(Wordsb, VCb, 1344, 1024, xt * 64, yt * 64, 0, 8,
               xt * 64, yt * 64, sA, sB, CPat, nullptr, nullptr, 0);
    } else {
        for (int u = bid - 320; u < 384; u += 192) {
            if (u < 128) {                    // conv1 epilogue (4 slices, relu)
                int idx8 = u * 256 + tid;
                size_t base = (size_t)idx8 * 8;
                int nb = (int)(base & 1023);
                f32x4 s0 = *(const f32x4*)(c1b + nb);
                f32x4 s1 = *(const f32x4*)(c1b + nb + 4);
                #pragma unroll
                for (int z = 0; z < 4; z++) {
                    const float* p = CP1 + (size_t)z * CP1_SL + base;
                    s0 += *(const f32x4*)p;
                    s1 += *(const f32x4*)(p + 4);
                }
                bf16x8 o;
                #pragma unroll
                for (int e = 0; e < 4; e++) {
                    o[e]     = (bf16_t)fmaxf(s0[e], 0.f);
                    o[4 + e] = (bf16_t)fmaxf(s1[e], 0.f);
                }
                *(bf16x8*)(A2b + base) = o;
            } else {                          // rownorm rows 0..1023
                int r = (u - 128) * 4 + wave;
                rownorm_row(VCb, VN, r, tid);
            }
        }
    }
    __threadfence(); grid.sync();

    // --- P5: conv2 splitK x4 -> CP2 || c1d1 -> VCb[1024..1280) || sim0 --------
    if (bid < 64) {
        int z = bid >> 4, yt = bid & 15;
        gemm64(A2b, WT2, 1024, 4096, 0, yt * 64, z * 1024, 8,
               0, yt * 64, sA, sB, CP2 + (size_t)z * CP2_SL, nullptr, nullptr, 0);
    } else if (bid < 128) {
        int g = bid - 64;
        int xt = g & 3, yt = g >> 2;
        gemm64(A2b, C1b, 1024, 1024, xt * 64, yt * 64, 0, 8,
               1024 + xt * 64, yt * 64, sA, sB, nullptr, c1db, VCb, 0);
    } else if (bid < 384) {
        int s = bid - 128;                    // 256 units: cols 0..1023
        int i = s >> 2, seg = s & 3;
        float* Gs  = (float*)smem;
        float* msk = Gs + 400;
        for (int q = tid; q < 400; q += 256) Gs[q] = GR[(size_t)i * 400 + q];
        if (tid < 20) msk[tid] = (wmask[i * 20 + tid] != 0) ? 1.f : 0.f;
        __syncthreads();
        sim_compute(i, seg * 256 + tid, CPat, VN, Gs, msk, SC, out);
    }
    __threadfence(); grid.sync();

    // ------ P6: conv2-epi -> A3b || attn1 (cols 1024..1280) || rownorm-mid ----
    if (bid < 32) {
        int idx8 = bid * 256 + tid;           // 8192 idx8 = 65536 elems
        size_t base = (size_t)idx8 * 8;
        int nb = (int)(base & 1023);
        f32x4 s0 = *(const f32x4*)(c2b + nb);
        f32x4 s1 = *(const f32x4*)(c2b + nb + 4);
        #pragma unroll
        for (int z = 0; z < 4; z++) {
            const float* p = CP2 + (size_t)z * CP2_SL + base;
            s0 += *(const f32x4*)p;
            s1 += *(const f32x4*)(p + 4);
        }
        bf16x8 o;
        #pragma unroll
        for (int e = 0; e < 4; e++) {
            o[e]     = (bf16_t)fmaxf(s0[e], 0.f);
            o[4 + e] = (bf16_t)fmaxf(s1[e], 0.f);
        }
        *(bf16x8*)(A3b + base) = o;
    } else if (bid < 112) {
        int g = bid - 32;                     // 0..79
        int xt = g % 20, yt = g / 20;
        gemm64(Wordsb, VCb, 1344, 1024, xt * 64, 1024 + yt * 64, 0, 8,
               xt * 64, 1024 + yt * 64, sA, sB, CPat, nullptr, nullptr, 0);
    } else if (bid < 176) {
        int r = 1024 + (bid - 112) * 4 + wave;
        rownorm_row(VCb, VN, r, tid);
    }
    __threadfence(); grid.sync();

    // ---------------- P7: c1d2 -> VCb[1280..) || fc -> GV || sim-mid ----------
    if (bid < 16) {
        gemm64(A3b, C1b, 1024, 1024, 0, bid * 64, 0, 8,
               1280, bid * 64, sA, sB, nullptr, c1db, VCb, 0);
    } else if (bid < 32) {
        int yt = bid - 16;
        gemm64(A3b, Fb, 1024, 1024, 0, yt * 64, 0, 8,
               0, yt * 64, sA, sB, GV, fcb, nullptr, 0);
    } else if (bid < 96) {
        int i = bid - 32;
        float* Gs  = (float*)smem;
        float* msk = Gs + 400;
        for (int q = tid; q < 400; q += 256) Gs[q] = GR[(size_t)i * 400 + q];
        if (tid < 20) msk[tid] = (wmask[i * 20 + tid] != 0) ? 1.f : 0.f;
        __syncthreads();
        sim_compute(i, 1024 + tid, CPat, VN, Gs, msk, SC, out);
    }
    __threadfence(); grid.sync();

    // ---------------- P8: attn2 || rownorm-hi || gscore -----------------------
    if (bid < 20) {
        gemm64(Wordsb, VCb, 1344, 1024, bid * 64, 1280, 0, 8,
               bid * 64, 1280, sA, sB, CPat, nullptr, nullptr, 0);
    } else if (bid < 36) {
        int r = 1280 + (bid - 20) * 4 + wave;
        rownorm_row(VCb, VN, r, tid);
    } else {
        for (int item = (bid - 36) * 4 + wave; item < 4096; item += 1904) {
            int i = item >> 6, j = item & 63;
            const float* a = sent + (size_t)i * 1024;
            const float* b = GV + (size_t)j * 1024;
            float sab = 0.f, saa = 0.f, sbb = 0.f;
            #pragma unroll
            for (int q = 0; q < 16; q++) {
                int d = lane + 64 * q;
                float av = a[d], bv = b[d];
                sab += av * bv; saa += av * av; sbb += bv * bv;
            }
            #pragma unroll
            for (int o = 32; o; o >>= 1) {
                sab += __shfl_xor(sab, o, 64);
                saa += __shfl_xor(saa, o, 64);
                sbb += __shfl_xor(sbb, o, 64);
            }
            if (lane == 0)
                GS[item] = sab / (fmaxf(sqrtf(saa), 1e-8f) * fmaxf(sqrtf(sbb), 1e-8f));
        }
    }
    __threadfence(); grid.sync();

    // ---------------- P9: sim-hi (cols 1280..1344) ----------------------------
    if (bid < 64) {
        float* Gs  = (float*)smem;
        float* msk = Gs + 400;
        for (int q = tid; q < 400; q += 256) Gs[q] = GR[(size_t)bid * 400 + q];
        if (tid < 20) msk[tid] = (wmask[bid * 20 + tid] != 0) ? 1.f : 0.f;
        __syncthreads();
        if (tid < 64) sim_compute(bid, 1280 + tid, CPat, VN, Gs, msk, SC, out);
    }
    __threadfence(); grid.sync();

    // ---------------- P10: margin ranking loss (block 0) ----------------------
    if (bid == 0) {
        float* Ld1 = (float*)smem;
        float* Ld2 = Ld1 + 64;
        float* red = Ld2 + 64;
        if (tid < 64) { Ld1[tid] = SC[tid * 65]; Ld2[tid] = GS[tid * 65]; }
        __syncthreads();
        float acc = 0.f;
        for (int idx = tid; idx < 4096; idx += 256) {
            int i = idx >> 6, j = idx & 63;
            if (i != j) {
                float s = SC[idx];
                acc += fmaxf(0.2f + s - Ld1[i], 0.f) + fmaxf(0.2f + s - Ld1[j], 0.f);
                float g = GS[idx];
                acc += fmaxf(0.2f + g - Ld2[i], 0.f) + fmaxf(0.2f + g - Ld2[j], 0.f);
            }
        }
        #pragma unroll
        for (int o = 32; o; o >>= 1) acc += __shfl_xor(acc, o, 64);
        if ((tid & 63) == 0) red[tid >> 6] = acc;
        __syncthreads();
        if (tid == 0) out[0] = (red[0] + red[1] + red[2] + red[3]) * (1.0f / 64.0f);
    }
}

// =============================================================================
//                 FALLBACK: classic 9-dispatch chain (R6 kernels)
// =============================================================================
__global__ __launch_bounds__(256) void prep0_kernel(
    const float* __restrict__ c0w, bf16_t* __restrict__ WT0,
    const float* __restrict__ video, bf16_t* __restrict__ Vb)
{
    __shared__ __align__(16) bf16_t lds[16384];
    int bx = blockIdx.x;
    if (bx < 256) wtrans4(c0w, WT0, bx * 4, threadIdx.x, lds);
    else          cast8(video, Vb, (bx - 256) * 256 + threadIdx.x);
}

__global__ __launch_bounds__(256) void d2_kernel(
    const bf16_t* __restrict__ Vb, const bf16_t* __restrict__ WT0, float* __restrict__ CP0,
    const float* __restrict__ c1w, const float* __restrict__ c2w,
    bf16_t* __restrict__ WT1, bf16_t* __restrict__ WT2,
    const float* __restrict__ words, bf16_t* __restrict__ Wordsb,
    const float* __restrict__ c1dw, bf16_t* __restrict__ C1b,
    const float* __restrict__ fcw, bf16_t* __restrict__ Fb)
{
    __shared__ __align__(16) bf16_t smem[32768];
    const int bx = blockIdx.x, tid = threadIdx.x;
    if (bx < 256) {
        bf16_t* sA = smem;
        bf16_t* sB = smem + 16384;
        const int z = bx >> 6, rem = bx & 63, xt = rem & 7, yt = rem >> 3;
        const int m0 = xt * 128, n0 = yt * 128, k0 = z * 1024;
        const int lane = tid & 63, wave = tid >> 6;
        const int sr = tid >> 3, pc = tid & 7, lc = pc ^ (sr & 7);
        const bf16_t* Ag = Vb  + (size_t)(m0 + sr) * 4096 + k0 + lc * 8;
        const bf16_t* Bg = WT0 + (size_t)(n0 + sr) * 4096 + k0 + lc * 8;
        const size_t rowskip = (size_t)32 * 4096;
        const int wrow = (wave >> 1) * 64, wcol = (wave & 1) * 64;
        const int fm = lane & 15, cb = lane >> 4;
        int offA[2][4], offB[2][4];
        #pragma unroll
        for (int h = 0; h < 2; h++)
            #pragma unroll
            for (int m = 0; m < 4; m++) {
                offA[h][m] = swz(wrow + m * 16 + fm, cb + h * 4);
                offB[h][m] = swz(wcol + m * 16 + fm, cb + h * 4);
            }
        f32x4 acc[4][4];
        #pragma unroll
        for (int m = 0; m < 4; m++)
            #pragma unroll
            for (int n = 0; n < 4; n++) acc[m][n] = (f32x4){0.f, 0.f, 0.f, 0.f};
        #pragma unroll
        for (int g = 0; g < 4; g++) {
            gload_lds16(Ag + g * rowskip, &sA[tid * 8 + g * 2048]);
            gload_lds16(Bg + g * rowskip, &sB[tid * 8 + g * 2048]);
        }
        for (int it = 0; it < 16; ++it) {
            const int buf = it & 1;
            __syncthreads();
            if (it < 15) {
                const bf16_t* a = Ag + (it + 1) * 64;
                const bf16_t* b = Bg + (it + 1) * 64;
                #pragma unroll
                for (int g = 0; g < 4; g++) {
                    gload_lds16(a + g * rowskip, &sA[(buf ^ 1) * 8192 + tid * 8 + g * 2048]);
                    gload_lds16(b + g * rowskip, &sB[(buf ^ 1) * 8192 + tid * 8 + g * 2048]);
                }
            }
            #pragma unroll
            for (int h = 0; h < 2; h++) {
                bf16x8 av[4], bv[4];
                #pragma unroll
                for (int m = 0; m < 4; m++) {
                    av[m] = *(const bf16x8*)&sA[buf * 8192 + offA[h][m]];
                    bv[m] = *(const bf16x8*)&sB[buf * 8192 + offB[h][m]];
                }
                #pragma unroll
                for (int m = 0; m < 4; m++)
                    #pragma unroll
                    for (int n = 0; n < 4; n++)
                        acc[m][n] = MFMA16(av[m], bv[n], acc[m][n]);
            }
        }
        float* Cz = CP0 + (size_t)z * CP0_SL;
        #pragma unroll
        for (int m = 0; m < 4; m++)
            #pragma unroll
            for (int rr = 0; rr < 4; rr++) {
                int gm = m0 + wrow + m * 16 + cb * 4 + rr;
                #pragma unroll
                for (int n = 0; n < 4; n++) {
                    int cg = n0 + wcol + n * 16 + fm;
                    Cz[(size_t)gm * 1024 + cg] = acc[m][n][rr];
                }
            }
    } else if (bx < 768) {
        int b2 = bx - 256;
        if (b2 < 256) wtrans4(c1w, WT1, b2 * 4, tid, smem);
        else          wtrans4(c2w, WT2, (b2 - 256) * 4, tid, smem);
    } else {
        int b2 = bx - 768;
        if (b2 < 640)       cast8(words, Wordsb, b2 * 256 + tid);
        else if (b2 < 1152) cast8(c1dw, C1b, (b2 - 640) * 256 + tid);
        else                cast8(fcw, Fb, (b2 - 1152) * 256 + tid);
    }
}

__global__ __launch_bounds__(256) void d3_kernel(
    const float* __restrict__ CP0, const float* __restrict__ c0b,
    bf16_t* __restrict__ Astack, const bf16_t* __restrict__ Wordsb,
    float* __restrict__ GR, float* __restrict__ SC)
{
    int bx = blockIdx.x, tid = threadIdx.x;
    if (bx < 512) {
        int idx8 = bx * 256 + tid;
        size_t base = (size_t)idx8 * 8;
        int nb = (int)(base & 1023);
        f32x4 s0 = *(const f32x4*)(c0b + nb);
        f32x4 s1 = *(const f32x4*)(c0b + nb + 4);
        #pragma unroll
        for (int z = 0; z < 4; z++) {
            const float* p = CP0 + (size_t)z * CP0_SL + base;
            s0 += *(const f32x4*)p;
            s1 += *(const f32x4*)(p + 4);
        }
        bf16x8 o;
        #pragma unroll
        for (int e = 0; e < 4; e++) {
            o[e]     = (bf16_t)fmaxf(s0[e], 0.f);
            o[4 + e] = (bf16_t)fmaxf(s1[e], 0.f);
        }
        *(bf16x8*)(Astack + base) = o;
    } else if (bx < 6912) {
        int g = bx - 512;
        int i = g / 100, piece = g % 100;
        int wave = tid >> 6, lane = tid & 63;
        int pair = piece * 4 + wave;
        gram_pair(Wordsb, GR, i * 400 + pair, lane);
    } else {
        int idx = (bx - 6912) * 1024 + tid * 4;
        *(f32x4*)(SC + idx) = (f32x4){0.f, 0.f, 0.f, 0.f};
    }
}

__global__ __launch_bounds__(256) void d4_kernel(
    const bf16_t* __restrict__ Astack, const bf16_t* __restrict__ WT1,
    const float* __restrict__ c1b, bf16_t* __restrict__ A2b,
    const bf16_t* __restrict__ C1b, const float* __restrict__ c1db,
    bf16_t* __restrict__ VCb)
{
    __shared__ __align__(16) bf16_t smem[32768];
    bf16_t* sA = smem; bf16_t* sB = smem + 16384;
    int bx = blockIdx.x;
    if (bx < 64) {
        int xt = bx & 3, yt = bx >> 2;
        gemm64(Astack, WT1, 1024, 4096, xt * 64, yt * 64, 0, 32,
               xt * 64, yt * 64, sA, sB, nullptr, c1b, A2b, 1);
    } else {
        int b2 = bx - 64;
        int xt = b2 & 15, yt = b2 >> 4;
        gemm64(Astack, C1b, 1024, 1024, xt * 64, yt * 64, 0, 8,
               xt * 64, yt * 64, sA, sB, nullptr, c1db, VCb, 0);
    }
}

__global__ __launch_bounds__(256) void d6_kernel(
    const bf16_t* __restrict__ A2b, const bf16_t* __restrict__ WT2,
    const float* __restrict__ c2b, bf16_t* __restrict__ A3b,
    const bf16_t* __restrict__ C1b, const float* __restrict__ c1db,
    const bf16_t* __restrict__ Wordsb, bf16_t* __restrict__ VCb,
    float* __restrict__ CPat, float* __restrict__ VN)
{
    __shared__ __align__(16) bf16_t smem[32768];
    bf16_t* sA = smem; bf16_t* sB = smem + 16384;
    int bx = blockIdx.x, tid = threadIdx.x;
    if (bx < 16) {
        gemm64(A2b, WT2, 1024, 4096, 0, bx * 64, 0, 32,
               0, bx * 64, sA, sB, nullptr, c2b, A3b, 1);
    } else if (bx < 336) {
        int g = bx - 16;
        int xt = g % 20, yt = g / 20;
        gemm64(Wordsb, VCb, 1344, 1024, xt * 64, yt * 64, 0, 8,
               xt * 64, yt * 64, sA, sB, CPat, nullptr, nullptr, 0);
    } else if (bx < 400) {
        int g = bx - 336;
        int xt = g & 3, yt = g >> 2;
        gemm64(A2b, C1b, 1024, 1024, xt * 64, yt * 64, 0, 8,
               1024 + xt * 64, yt * 64, sA, sB, nullptr, c1db, VCb, 0);
    } else {
        int r = (bx - 400) * 4 + (tid >> 6);
        rownorm_row(VCb, VN, r, tid);
    }
}

__global__ __launch_bounds__(256) void d7_kernel(
    const bf16_t* __restrict__ A3b, const bf16_t* __restrict__ C1b,
    const bf16_t* __restrict__ Fb,
    const float* __restrict__ c1db, const float* __restrict__ fcb,
    bf16_t* __restrict__ VCb, float* __restrict__ GV,
    const bf16_t* __restrict__ Wordsb, float* __restrict__ CPat,
    const float* __restrict__ GR, float* __restrict__ VN,
    const int* __restrict__ wmask, float* __restrict__ SC, float* __restrict__ out)
{
    __shared__ __align__(16) bf16_t smem[32768];
    bf16_t* sA = smem; bf16_t* sB = smem + 16384;
    const int bx = blockIdx.x, tid = threadIdx.x;
    if (bx < 16) {
        gemm64(A3b, C1b, 1024, 1024, 0, bx * 64, 0, 8,
               1280, bx * 64, sA, sB, nullptr, c1db, VCb, 0);
    } else if (bx < 32) {
        int yt = bx - 16;
        gemm64(A3b, Fb, 1024, 1024, 0, yt * 64, 0, 8,
               0, yt * 64, sA, sB, GV, fcb, nullptr, 0);
    } else if (bx < 112) {
        int g = bx - 32;
        int xt = g % 20, yt = g / 20;
        gemm64(Wordsb, VCb, 1344, 1024, xt * 64, 1024 + yt * 64, 0, 8,
               xt * 64, 1024 + yt * 64, sA, sB, CPat, nullptr, nullptr, 0);
    } else if (bx < 368) {
        int s = bx - 112;
        int i = s >> 2, seg = s & 3;
        float* Gs  = (float*)smem;
        float* msk = Gs + 400;
        for (int q = tid; q < 400; q += 256) Gs[q] = GR[(size_t)i * 400 + q];
        if (tid < 20) msk[tid] = (wmask[i * 20 + tid] != 0) ? 1.f : 0.f;
        __syncthreads();
        sim_compute(i, seg * 256 + tid, CPat, VN, Gs, msk, SC, out);
    } else {
        int r = 1024 + (bx - 368) * 4 + (tid >> 6);
        rownorm_row(VCb, VN, r, tid);
    }
}

__global__ __launch_bounds__(256) void d8_kernel(
    const bf16_t* __restrict__ Wordsb, const bf16_t* __restrict__ VCb,
    float* __restrict__ CPat, float* __restrict__ VN,
    const float* __restrict__ sent, const float* __restrict__ GV,
    float* __restrict__ GS, const float* __restrict__ GR,
    const int* __restrict__ wmask, float* __restrict__ SC, float* __restrict__ out)
{
    __shared__ __align__(16) bf16_t smem[32768];
    bf16_t* sA = smem; bf16_t* sB = smem + 16384;
    int bx = blockIdx.x, tid = threadIdx.x;
    if (bx < 20) {
        gemm64(Wordsb, VCb, 1344, 1024, bx * 64, 1280, 0, 8,
               bx * 64, 1280, sA, sB, CPat, nullptr, nullptr, 0);
    } else if (bx < 36) {
        int r = 1280 + (bx - 20) * 4 + (tid >> 6);
        rownorm_row(VCb, VN, r, tid);
    } else if (bx < 1060) {
        int item = (bx - 36) * 4 + (tid >> 6);
        int i = item >> 6, j = item & 63;
        int lane = tid & 63;
        const float* a = sent + (size_t)i * 1024;
        const float* b = GV + (size_t)j * 1024;
        float sab = 0.f, saa = 0.f, sbb = 0.f;
        #pragma unroll
        for (int q = 0; q < 16; q++) {
            int d = lane + 64 * q;
            float av = a[d], bv = b[d];
            sab += av * bv; saa += av * av; sbb += bv * bv;
        }
        #pragma unroll
        for (int o = 32; o; o >>= 1) {
            sab += __shfl_xor(sab, o, 64);
            saa += __shfl_xor(saa, o, 64);
            sbb += __shfl_xor(sbb, o, 64);
        }
        if (lane == 0)
            GS[item] = sab / (fmaxf(sqrtf(saa), 1e-8f) * fmaxf(sqrtf(sbb), 1e-8f));
    } else {
        int i = bx - 1060;
        float* Gs  = (float*)smem;
        float* msk = Gs + 400;
        for (int q = tid; q < 400; q += 256) Gs[q] = GR[(size_t)i * 400 + q];
        if (tid < 20) msk[tid] = (wmask[i * 20 + tid] != 0) ? 1.f : 0.f;
        __syncthreads();
        sim_compute(i, 1024 + tid, CPat, VN, Gs, msk, SC, out);
    }
}

__global__ __launch_bounds__(256) void d9_kernel(
    const float* __restrict__ CPat, const float* __restrict__ GR,
    const float* __restrict__ VN, const int* __restrict__ wmask,
    float* __restrict__ SC, float* __restrict__ out)
{
    __shared__ float Gs[400];
    __shared__ float msk[20];
    int i = blockIdx.x, tid = threadIdx.x;
    for (int q = tid; q < 400; q += 256) Gs[q] = GR[(size_t)i * 400 + q];
    if (tid < 20) msk[tid] = (wmask[i * 20 + tid] != 0) ? 1.f : 0.f;
    __syncthreads();
    if (tid < 64) sim_compute(i, 1280 + tid, CPat, VN, Gs, msk, SC, out);
}

__global__ __launch_bounds__(256) void loss_kernel(
    const float* __restrict__ SC_, const float* __restrict__ GS_,
    float* __restrict__ out)
{
    __shared__ float d1[64], d2[64], red[4];
    int tid = threadIdx.x;
    if (tid < 64) { d1[tid] = SC_[tid * 65]; d2[tid] = GS_[tid * 65]; }
    __syncthreads();
    float acc = 0.f;
    for (int idx = tid; idx < 4096; idx += 256) {
        int i = idx >> 6, j = idx & 63;
        if (i != j) {
            float s = SC_[idx];
            acc += fmaxf(0.2f + s - d1[i], 0.f) + fmaxf(0.2f + s - d1[j], 0.f);
            float g = GS_[idx];
            acc += fmaxf(0.2f + g - d2[i], 0.f) + fmaxf(0.2f + g - d2[j], 0.f);
        }
    }
    #pragma unroll
    for (int o = 32; o; o >>= 1) acc += __shfl_xor(acc, o, 64);
    if ((tid & 63) == 0) red[tid >> 6] = acc;
    __syncthreads();
    if (tid == 0) out[0] = (red[0] + red[1] + red[2] + red[3]) * (1.0f / 64.0f);
}

// ------------------------------------------------------------------------------
extern "C" void kernel_launch(void* const* d_in, const int* in_sizes, int n_in,
                              void* d_out, int out_size, void* d_ws, size_t ws_size,
                              hipStream_t stream)
{
    const float* video     = (const float*)d_in[0];
    const float* words     = (const float*)d_in[1];
    const int*   w_masks   = (const int*)  d_in[2];
    const float* sentences = (const float*)d_in[3];
    const float* conv0_w   = (const float*)d_in[4];
    const float* conv0_b   = (const float*)d_in[5];
    const float* conv1_w   = (const float*)d_in[6];
    const float* conv1_b   = (const float*)d_in[7];
    const float* conv2_w   = (const float*)d_in[8];
    const float* conv2_b   = (const float*)d_in[9];
    const float* conv1d_w  = (const float*)d_in[10];
    const float* conv1d_b  = (const float*)d_in[11];
    const float* fc_w      = (const float*)d_in[12];
    const float* fc_b      = (const float*)d_in[13];
    float* out = (float*)d_out;
    float* ws = (float*)d_ws;

    // ---- flat workspace (float units) ----------------------------------------
    bf16_t* WT0    = (bf16_t*)(ws + 0);            // 1024x4096 bf16
    bf16_t* WT1    = (bf16_t*)(ws + 2097152);
    bf16_t* WT2    = (bf16_t*)(ws + 4194304);
    bf16_t* Vb     = (bf16_t*)(ws + 6291456);      // 4096x1024 bf16
    bf16_t* Wordsb = (bf16_t*)(ws + 8388608);      // 1,310,720 bf16
    bf16_t* C1b    = (bf16_t*)(ws + 9043968);      // 1,048,576 bf16
    bf16_t* Fb     = (bf16_t*)(ws + 9568256);      // 1,048,576 bf16
    bf16_t* Astack = (bf16_t*)(ws + 10092544);     // 1024x1024 bf16 (conv0 out)
    bf16_t* A2b    = (bf16_t*)(ws + 10616832);     // 256x1024 bf16 (conv1 out)
    bf16_t* A3b    = (bf16_t*)(ws + 10747904);     // 64x1024 bf16 (conv2 out)
    bf16_t* VCb    = (bf16_t*)(ws + 10780672);     // 1344x1024 bf16 (STACKED)
    float*  CP0    = ws + 11468800;                // 8 x 1,048,576 f
    float*  CP1    = ws + 19857408;                // 4 x 262,144 f
    float*  CP2    = ws + 20905984;                // 4 x 65,536 f
    float*  CPat   = ws + 21168128;                // 1,720,320 f (single slice)
    float*  VN     = ws + 22888448;                // 1,344
    float*  GR     = ws + 22889792;                // 25,600
    float*  SC     = ws + 22915392;                // 4,096
    float*  GV     = ws + 22919488;                // 65,536
    float*  GS     = ws + 22985024;                // 4,096 (ends 22,989,120)

    dim3 blk(256);

    // ---- try the cooperative mega-kernel (one dispatch, 11 phases) -----------
    void* args[] = {
        (void*)&video, (void*)&words, (void*)&w_masks, (void*)&sentences,
        (void*)&conv0_w, (void*)&conv0_b, (void*)&conv1_w, (void*)&conv1_b,
        (void*)&conv2_w, (void*)&conv2_b, (void*)&conv1d_w, (void*)&conv1d_b,
        (void*)&fc_w, (void*)&fc_b,
        (void*)&WT0, (void*)&WT1, (void*)&WT2, (void*)&Vb, (void*)&Wordsb,
        (void*)&C1b, (void*)&Fb, (void*)&Astack, (void*)&A2b, (void*)&A3b,
        (void*)&VCb, (void*)&CP0, (void*)&CP1, (void*)&CP2, (void*)&CPat,
        (void*)&VN, (void*)&GR, (void*)&SC, (void*)&GV, (void*)&GS, (void*)&out
    };
    hipError_t err = hipLaunchCooperativeKernel(
        (void*)mega_kernel, dim3(512), blk, args, 0, stream);
    if (err == hipSuccess) return;
    (void)hipGetLastError();   // clear error state, fall back to classic chain

    prep0_kernel<<<2304, blk, 0, stream>>>(conv0_w, WT0, video, Vb);
    d2_kernel<<<2432, blk, 0, stream>>>(Vb, WT0, CP0, conv1_w, conv2_w, WT1, WT2,
                                        words, Wordsb, conv1d_w, C1b, fc_w, Fb);
    d3_kernel<<<6916, blk, 0, stream>>>(CP0, conv0_b, Astack, Wordsb, GR, SC);
    d4_kernel<<<320, blk, 0, stream>>>(Astack, WT1, conv1_b, A2b, C1b, conv1d_b, VCb);
    d6_kernel<<<656, blk, 0, stream>>>(A2b, WT2, conv2_b, A3b, C1b, conv1d_b,
                                       Wordsb, VCb, CPat, VN);
    d7_kernel<<<432, blk, 0, stream>>>(A3b, C1b, Fb, conv1d_b, fc_b,
                                       VCb, GV, Wordsb, CPat, GR, VN, w_masks, SC, out);
    d8_kernel<<<1124, blk, 0, stream>>>(Wordsb, VCb, CPat, VN, sentences, GV, GS,
                                        GR, w_masks, SC, out);
    d9_kernel<<<64, blk, 0, stream>>>(CPat, GR, VN, w_masks, SC, out);
    loss_kernel<<<1, blk, 0, stream>>>(SC, GS, out);
}

// Round 8
// 241.193 us; speedup vs baseline: 5.4813x; 5.4813x over previous
//
#include <hip/hip_runtime.h>
#include <cmath>
#include <cstdint>

// B=64, T=64, W=20, D=1024, K=4, STRIDE=4 ; conv lengths 64->16->4->1 ; T_total=21

typedef __bf16 bf16_t;
typedef bf16_t bf16x8 __attribute__((ext_vector_type(8)));
typedef bf16_t bf16x4 __attribute__((ext_vector_type(4)));
typedef bf16_t bf16x2 __attribute__((ext_vector_type(2)));
typedef float  f32x4  __attribute__((ext_vector_type(4)));

__device__ __forceinline__ void gload_lds16(const void* g, void* l) {
    __builtin_amdgcn_global_load_lds(
        (const __attribute__((address_space(1))) void*)g,
        (__attribute__((address_space(3))) void*)l, 16, 0, 0);
}

// swizzled LDS offset (bf16 units): physical chunk = c ^ (row&7). [R3: conflicts->0]
__device__ __forceinline__ int swz(int r, int c) { return (r * 8 + (c ^ (r & 7))) * 8; }

// conv1d stack row remap -> VC row j*21 + t
__device__ __forceinline__ int remap1(int gm) {
    if (gm < 1024) return (gm >> 4) * 21 + (gm & 15);
    if (gm < 1280) { int g = gm - 1024; return (g >> 2) * 21 + 16 + (g & 3); }
    return (gm - 1280) * 21 + 20;
}

// ---------------- LDS-staged (i,k)->(k,i) weight transpose, 4 o-rows/block ----
// wt[o][k*1024+i] = w[o][i*4+k].  Coalesced reads AND writes (replaces the
// scattered 2-byte-store transpose: each old wave store touched 64 cache lines).
__device__ __forceinline__ void wtrans4(const float* __restrict__ w,
                                        bf16_t* __restrict__ wt,
                                        int o0, int tid, bf16_t* lds /*16384*/)
{
    #pragma unroll
    for (int oo = 0; oo < 4; oo++) {
        const float* src = w + ((size_t)(o0 + oo) << 12);
        #pragma unroll
        for (int q = 0; q < 2; q++) {
            f32x4 va = *(const f32x4*)(src + tid * 16 + q * 8);      // i = tid*4+2q
            f32x4 vb = *(const f32x4*)(src + tid * 16 + q * 8 + 4);  // i = tid*4+2q+1
            int ib = tid * 4 + 2 * q;
            #pragma unroll
            for (int k = 0; k < 4; k++) {
                bf16x2 p2 = { (bf16_t)va[k], (bf16_t)vb[k] };
                *(bf16x2*)(lds + oo * 4096 + k * 1024 + ib) = p2;
            }
        }
    }
    __syncthreads();
    #pragma unroll
    for (int oo = 0; oo < 4; oo++) {
        bf16x8 v0 = *(bf16x8*)(lds + oo * 4096 + tid * 16);
        bf16x8 v1 = *(bf16x8*)(lds + oo * 4096 + tid * 16 + 8);
        bf16_t* dst = wt + ((size_t)(o0 + oo) << 12) + tid * 16;
        *(bf16x8*)dst       = v0;
        *(bf16x8*)(dst + 8) = v1;
    }
}

// ---------------- prep: 3 weight transposes (LDS-staged) + 4 casts ------------
__global__ __launch_bounds__(256) void prep_kernel(
    const float* __restrict__ c0w, const float* __restrict__ c1w,
    const float* __restrict__ c2w,
    bf16_t* __restrict__ WT0, bf16_t* __restrict__ WT1, bf16_t* __restrict__ WT2,
    const float* __restrict__ video, bf16_t* __restrict__ Vb,
    const float* __restrict__ words, bf16_t* __restrict__ Wordsb,
    const float* __restrict__ c1dw, bf16_t* __restrict__ C1b,
    const float* __restrict__ fcw, bf16_t* __restrict__ Fb)
{
    __shared__ __align__(16) bf16_t lds[16384];
    int bx = blockIdx.x;
    if (bx < 768) {                         // LDS-staged transposes
        if (bx < 256)      wtrans4(c0w, WT0, bx * 4, threadIdx.x, lds);
        else if (bx < 512) wtrans4(c1w, WT1, (bx - 256) * 4, threadIdx.x, lds);
        else               wtrans4(c2w, WT2, (bx - 512) * 4, threadIdx.x, lds);
    } else {                                // casts, 4 elems/thread
        int b2 = bx - 768;
        const float* s; bf16_t* d;
        if (b2 < 4096)      { s = video; d = Vb; }
        else if (b2 < 5376) { s = words; d = Wordsb; b2 -= 4096; }
        else if (b2 < 6400) { s = c1dw;  d = C1b;    b2 -= 5376; }
        else                { s = fcw;   d = Fb;     b2 -= 6400; }
        int off = (b2 * 256 + threadIdx.x) * 4;
        float4 v = *(const float4*)(s + off);
        bf16x4 o4 = { (bf16_t)v.x, (bf16_t)v.y, (bf16_t)v.z, (bf16_t)v.w };
        *(bf16x4*)(d + off) = o4;
    }
}

// ---------------- 64x64 bf16 MFMA NT split-K GEMM (double-buffered) ----------
__global__ __launch_bounds__(256) void mgemm_kernel(
    const bf16_t* __restrict__ A, const bf16_t* __restrict__ B,
    const bf16_t* __restrict__ B2, float* __restrict__ CP,
    int N, int K, int Kchunk, int fcTile, int aRow0, int cpSlice)
{
    __shared__ __align__(16) bf16_t sA[2][4096];
    __shared__ __align__(16) bf16_t sB[2][4096];
    const int tid  = threadIdx.x;
    const int lane = tid & 63;
    const int wave = tid >> 6;
    const int bx = blockIdx.x;
    const int m0C = bx * 64;
    int m0A = m0C;
    const bf16_t* Buse = B;
    if (bx == fcTile) { m0A = aRow0; Buse = B2; }
    const int n0 = blockIdx.y * 64;
    const int k0 = blockIdx.z * Kchunk;

    const int sr = tid >> 3;
    const int pc = tid & 7;
    const int lc = pc ^ (sr & 7);
    const bf16_t* Ag = A + (size_t)(m0A + sr) * K + lc * 8;
    const bf16_t* Bg = Buse + (size_t)(n0 + sr) * K + lc * 8;
    const size_t rowskip = (size_t)32 * K;

    const int wr = (wave >> 1) * 32;
    const int wc = (wave & 1) * 32;
    const int fm = lane & 15;
    const int cb = lane >> 4;

    int offA[2][2], offB[2][2];
    #pragma unroll
    for (int h = 0; h < 2; h++) {
        offA[h][0] = swz(wr +      fm, cb + h * 4);
        offA[h][1] = swz(wr + 16 + fm, cb + h * 4);
        offB[h][0] = swz(wc +      fm, cb + h * 4);
        offB[h][1] = swz(wc + 16 + fm, cb + h * 4);
    }

    f32x4 acc[2][2];
    #pragma unroll
    for (int a = 0; a < 2; a++)
        #pragma unroll
        for (int b = 0; b < 2; b++) acc[a][b] = (f32x4){0.f, 0.f, 0.f, 0.f};

    const int nIt = Kchunk >> 6;
    {
        const bf16_t* a = Ag + k0; const bf16_t* b = Bg + k0;
        gload_lds16(a,           &sA[0][tid * 8]);
        gload_lds16(a + rowskip, &sA[0][2048 + tid * 8]);
        gload_lds16(b,           &sB[0][tid * 8]);
        gload_lds16(b + rowskip, &sB[0][2048 + tid * 8]);
    }
    for (int it = 0; it < nIt; ++it) {
        const int buf = it & 1;
        __syncthreads();
        if (it + 1 < nIt) {
            const bf16_t* a = Ag + k0 + (it + 1) * 64;
            const bf16_t* b = Bg + k0 + (it + 1) * 64;
            bf16_t* dA = &sA[buf ^ 1][0];
            bf16_t* dB = &sB[buf ^ 1][0];
            gload_lds16(a,           dA + tid * 8);
            gload_lds16(a + rowskip, dA + 2048 + tid * 8);
            gload_lds16(b,           dB + tid * 8);
            gload_lds16(b + rowskip, dB + 2048 + tid * 8);
        }
        #pragma unroll
        for (int h = 0; h < 2; h++) {
            bf16x8 a0 = *(const bf16x8*)&sA[buf][offA[h][0]];
            bf16x8 a1 = *(const bf16x8*)&sA[buf][offA[h][1]];
            bf16x8 b0 = *(const bf16x8*)&sB[buf][offB[h][0]];
            bf16x8 b1 = *(const bf16x8*)&sB[buf][offB[h][1]];
            acc[0][0] = __builtin_amdgcn_mfma_f32_16x16x32_bf16(a0, b0, acc[0][0], 0, 0, 0);
            acc[0][1] = __builtin_amdgcn_mfma_f32_16x16x32_bf16(a0, b1, acc[0][1], 0, 0, 0);
            acc[1][0] = __builtin_amdgcn_mfma_f32_16x16x32_bf16(a1, b0, acc[1][0], 0, 0, 0);
            acc[1][1] = __builtin_amdgcn_mfma_f32_16x16x32_bf16(a1, b1, acc[1][1], 0, 0, 0);
        }
    }

    // C/D layout: col = lane&15, row = (lane>>4)*4 + reg   [verified m89/m91]
    float* Cz = CP + (size_t)blockIdx.z * cpSlice;
    #pragma unroll
    for (int im = 0; im < 2; im++)
        #pragma unroll
        for (int rr = 0; rr < 4; rr++) {
            int gm = m0C + wr + im * 16 + cb * 4 + rr;
            #pragma unroll
            for (int in_ = 0; in_ < 2; in_++) {
                int cg = n0 + wc + in_ * 16 + fm;
                Cz[(size_t)gm * N + cg] = acc[im][in_][rr];
            }
        }
}

// ------- attn GEMM (blocks <840) + rownorm (840..2183) + gram (>=2184) --------
__global__ __launch_bounds__(256) void attn_ng_kernel(
    const bf16_t* __restrict__ A, const bf16_t* __restrict__ B,
    float* __restrict__ CP,
    const bf16_t* __restrict__ VCb, float* __restrict__ VN,
    const bf16_t* __restrict__ Wb, float* __restrict__ G)
{
    __shared__ __align__(16) bf16_t sA[2][4096];
    __shared__ __align__(16) bf16_t sB[2][4096];
    __shared__ float red[4];
    const int bxg = blockIdx.x;
    const int tid = threadIdx.x;

    if (bxg < 840) {
        // ---- GEMM path: z = bxg/420, x = tile%20 (M), y = tile/20 (N) ----
        const int z = bxg / 420;
        const int rem = bxg - z * 420;
        const int xt = rem % 20, yt = rem / 20;
        const int lane = tid & 63;
        const int wave = tid >> 6;
        const int m0 = xt * 64, n0 = yt * 64;
        const int k0 = z * 512;
        const int N = 1344, K = 1024;

        const int sr = tid >> 3;
        const int pc = tid & 7;
        const int lc = pc ^ (sr & 7);
        const bf16_t* Ag = A + (size_t)(m0 + sr) * K + lc * 8;
        const bf16_t* Bg = B + (size_t)(n0 + sr) * K + lc * 8;
        const size_t rowskip = (size_t)32 * K;

        const int wr = (wave >> 1) * 32;
        const int wc = (wave & 1) * 32;
        const int fm = lane & 15;
        const int cb = lane >> 4;

        int offA[2][2], offB[2][2];
        #pragma unroll
        for (int h = 0; h < 2; h++) {
            offA[h][0] = swz(wr +      fm, cb + h * 4);
            offA[h][1] = swz(wr + 16 + fm, cb + h * 4);
            offB[h][0] = swz(wc +      fm, cb + h * 4);
            offB[h][1] = swz(wc + 16 + fm, cb + h * 4);
        }

        f32x4 acc[2][2];
        #pragma unroll
        for (int a = 0; a < 2; a++)
            #pragma unroll
            for (int b = 0; b < 2; b++) acc[a][b] = (f32x4){0.f, 0.f, 0.f, 0.f};

        {
            const bf16_t* a = Ag + k0; const bf16_t* b = Bg + k0;
            gload_lds16(a,           &sA[0][tid * 8]);
            gload_lds16(a + rowskip, &sA[0][2048 + tid * 8]);
            gload_lds16(b,           &sB[0][tid * 8]);
            gload_lds16(b + rowskip, &sB[0][2048 + tid * 8]);
        }
        for (int it = 0; it < 8; ++it) {
            const int buf = it & 1;
            __syncthreads();
            if (it + 1 < 8) {
                const bf16_t* a = Ag + k0 + (it + 1) * 64;
                const bf16_t* b = Bg + k0 + (it + 1) * 64;
                bf16_t* dA = &sA[buf ^ 1][0];
                bf16_t* dB = &sB[buf ^ 1][0];
                gload_lds16(a,           dA + tid * 8);
                gload_lds16(a + rowskip, dA + 2048 + tid * 8);
                gload_lds16(b,           dB + tid * 8);
                gload_lds16(b + rowskip, dB + 2048 + tid * 8);
            }
            #pragma unroll
            for (int h = 0; h < 2; h++) {
                bf16x8 a0 = *(const bf16x8*)&sA[buf][offA[h][0]];
                bf16x8 a1 = *(const bf16x8*)&sA[buf][offA[h][1]];
                bf16x8 b0 = *(const bf16x8*)&sB[buf][offB[h][0]];
                bf16x8 b1 = *(const bf16x8*)&sB[buf][offB[h][1]];
                acc[0][0] = __builtin_amdgcn_mfma_f32_16x16x32_bf16(a0, b0, acc[0][0], 0, 0, 0);
                acc[0][1] = __builtin_amdgcn_mfma_f32_16x16x32_bf16(a0, b1, acc[0][1], 0, 0, 0);
                acc[1][0] = __builtin_amdgcn_mfma_f32_16x16x32_bf16(a1, b0, acc[1][0], 0, 0, 0);
                acc[1][1] = __builtin_amdgcn_mfma_f32_16x16x32_bf16(a1, b1, acc[1][1], 0, 0, 0);
            }
        }

        float* Cz = CP + (size_t)z * 1720320;
        #pragma unroll
        for (int im = 0; im < 2; im++)
            #pragma unroll
            for (int rr = 0; rr < 4; rr++) {
                int gm = m0 + wr + im * 16 + cb * 4 + rr;
                #pragma unroll
                for (int in_ = 0; in_ < 2; in_++) {
                    int cg = n0 + wc + in_ * 16 + fm;
                    Cz[(size_t)gm * N + cg] = acc[im][in_][rr];
                }
            }
    } else if (bxg < 2184) {
        // ---- rownorm path: ||VCb row|| ----
        int r = bxg - 840;
        const bf16_t* x = VCb + ((size_t)r << 10);
        float s = 0.f;
        for (int d = tid; d < 1024; d += 256) { float v = (float)x[d]; s += v * v; }
        #pragma unroll
        for (int o = 32; o; o >>= 1) s += __shfl_xor(s, o, 64);
        if ((tid & 63) == 0) red[tid >> 6] = s;
        __syncthreads();
        if (tid == 0) VN[r] = sqrtf(red[0] + red[1] + red[2] + red[3]);
    } else {
        // ---- gram path: one wave per (w,w') pair ----
        int g = bxg - 2184;                // 0..6399
        int i = g / 100, piece = g % 100;
        int wave = tid >> 6, lane = tid & 63;
        int pair = piece * 4 + wave;       // 0..399
        int w = pair / 20, w2 = pair % 20;
        const bf16_t* a = Wb + (((size_t)i * 20 + w)  << 10) + lane * 16;
        const bf16_t* b = Wb + (((size_t)i * 20 + w2) << 10) + lane * 16;
        bf16x8 a0 = *(const bf16x8*)a, a1 = *(const bf16x8*)(a + 8);
        bf16x8 b0 = *(const bf16x8*)b, b1 = *(const bf16x8*)(b + 8);
        float s = 0.f;
        #pragma unroll
        for (int e = 0; e < 8; e++)
            s += (float)a0[e] * (float)b0[e] + (float)a1[e] * (float)b1[e];
        #pragma unroll
        for (int o = 32; o; o >>= 1) s += __shfl_xor(s, o, 64);
        if (lane == 0) G[(size_t)i * 400 + pair] = s;
    }
}

// ------- split-K reduce + bias + relu -> bf16 -------------------------------
__global__ void epilogueB_kernel(const float* __restrict__ CP_, int nz,
    const float* __restrict__ bias, bf16_t* __restrict__ D, int MN, int N, int relu)
{
    int idx = blockIdx.x * 256 + threadIdx.x;
    if (idx >= MN) return;
    int n = idx % N;
    float s = 0.f;
    for (int z = 0; z < nz; z++) s += CP_[(size_t)z * MN + idx];
    if (bias) s += bias[n];
    if (relu) s = fmaxf(s, 0.f);
    D[idx] = (bf16_t)s;
}

// ------- conv1d+fc combined epilogue (4 split-K slices) -----------------------
__global__ void epilogueCF_kernel(const float* __restrict__ CP_,
    const float* __restrict__ bias1, const float* __restrict__ biasf,
    bf16_t* __restrict__ VCb, float* __restrict__ GV)
{
    int idx = blockIdx.x * 256 + threadIdx.x;       // < 1441792
    int row = idx >> 10, n = idx & 1023;
    float s = CP_[idx] + CP_[idx + 1441792] + CP_[idx + 2 * 1441792] + CP_[idx + 3 * 1441792];
    if (row < 1344) VCb[(size_t)remap1(row) * 1024 + n] = (bf16_t)(s + bias1[n]);
    else            GV[(size_t)(row - 1344) * 1024 + n] = s + biasf[n];
}

// ---------------- sim: one THREAD per (i, jt); reads 2 split-K slices ---------
__global__ __launch_bounds__(256) void sim_kernel(
    const float* __restrict__ CPat, const float* __restrict__ G_,
    const float* __restrict__ VN_, const int* __restrict__ wmask,
    float* __restrict__ SA_)
{
    __shared__ float Gs[400];
    __shared__ float msk[20];
    const int i  = blockIdx.x;
    const int jt = blockIdx.y * 256 + threadIdx.x;   // 0..1535 (1344 used)
    for (int q = threadIdx.x; q < 400; q += 256) Gs[q] = G_[(size_t)i * 400 + q];
    if (threadIdx.x < 20) msk[threadIdx.x] = (wmask[i * 20 + threadIdx.x] != 0) ? 1.f : 0.f;
    __syncthreads();
    if (jt >= 1344) return;

    float s[20], p[20];
    float mx = -1e30f;
    #pragma unroll
    for (int w = 0; w < 20; w++) {
        size_t q = (size_t)(i * 20 + w) * 1344 + jt;
        s[w] = CPat[q] + CPat[q + 1720320];
        if (msk[w] != 0.f) mx = fmaxf(mx, s[w]);
    }
    float denom = 0.f, num = 0.f;
    #pragma unroll
    for (int w = 0; w < 20; w++) {
        p[w] = (msk[w] != 0.f) ? __expf(s[w] - mx) : 0.f;
        denom += p[w];
        num   += p[w] * s[w];
    }
    float quad = 0.f;
    #pragma unroll
    for (int w = 0; w < 20; w++) {
        float c = 0.f;
        #pragma unroll
        for (int w2 = 0; w2 < 20; w2++) c += Gs[w * 20 + w2] * p[w2];
        quad += p[w] * c;
    }
    float dot = num / denom;
    float vsn = sqrtf(fmaxf(quad, 0.f)) / denom;
    float sim = dot / (fmaxf(VN_[jt], 1e-8f) * fmaxf(vsn, 1e-8f));
    SA_[(size_t)i * 1344 + jt] = sim;
}

// ------- scores+positive_map (blocks <16) + gscore w/ algebraic norms (>=16) --
__global__ void sg_kernel(const float* __restrict__ SA_, float* __restrict__ SC_,
                          float* __restrict__ out,
                          const float* __restrict__ sent, const float* __restrict__ GV,
                          float* __restrict__ GS_)
{
    int bx = blockIdx.x;
    if (bx < 16) {
        int idx = bx * 256 + threadIdx.x;  // 4096 = i*64+j
        int i = idx >> 6, j = idx & 63;
        const float* row = SA_ + (size_t)idx * 21;
        float s = 0.f;
        #pragma unroll
        for (int t = 0; t < 21; t++) s += row[t];
        SC_[idx] = s * (1.0f / 21.0f);
        if (i == j) {
            #pragma unroll
            for (int t = 0; t < 21; t++) out[1 + i * 21 + t] = row[t];
        }
    } else {
        int item = (bx - 16) * 4 + (threadIdx.x >> 6);  // 4096
        int i = item >> 6, j = item & 63;
        int lane = threadIdx.x & 63;
        const float* a = sent + (size_t)i * 1024;
        const float* b = GV + (size_t)j * 1024;
        float sab = 0.f, saa = 0.f, sbb = 0.f;
        #pragma unroll
        for (int q = 0; q < 16; q++) {
            int d = lane + 64 * q;
            float av = a[d], bv = b[d];
            sab += av * bv; saa += av * av; sbb += bv * bv;
        }
        #pragma unroll
        for (int o = 32; o; o >>= 1) {
            sab += __shfl_xor(sab, o, 64);
            saa += __shfl_xor(saa, o, 64);
            sbb += __shfl_xor(sbb, o, 64);
        }
        if (lane == 0)
            GS_[item] = sab / (fmaxf(sqrtf(saa), 1e-8f) * fmaxf(sqrtf(sbb), 1e-8f));
    }
}

// ---------------- margin ranking loss -----------------------------------------
__global__ void loss_kernel(const float* __restrict__ SC_, const float* __restrict__ GS_,
                            float* __restrict__ out) {
    __shared__ float d1[64], d2[64], red[4];
    int tid = threadIdx.x;
    if (tid < 64) { d1[tid] = SC_[tid * 65]; d2[tid] = GS_[tid * 65]; }
    __syncthreads();
    float acc = 0.f;
    for (int idx = tid; idx < 4096; idx += 256) {
        int i = idx >> 6, j = idx & 63;
        if (i != j) {
            float s = SC_[idx];
            acc += fmaxf(0.2f + s - d1[i], 0.f) + fmaxf(0.2f + s - d1[j], 0.f);
            float g = GS_[idx];
            acc += fmaxf(0.2f + g - d2[i], 0.f) + fmaxf(0.2f + g - d2[j], 0.f);
        }
    }
    #pragma unroll
    for (int o = 32; o; o >>= 1) acc += __shfl_xor(acc, o, 64);
    if ((tid & 63) == 0) red[tid >> 6] = acc;
    __syncthreads();
    if (tid == 0) out[0] = (red[0] + red[1] + red[2] + red[3]) * (1.0f / 64.0f);
}

// ------------------------------------------------------------------------------
extern "C" void kernel_launch(void* const* d_in, const int* in_sizes, int n_in,
                              void* d_out, int out_size, void* d_ws, size_t ws_size,
                              hipStream_t stream)
{
    const float* video     = (const float*)d_in[0];
    const float* words     = (const float*)d_in[1];
    const int*   w_masks   = (const int*)  d_in[2];
    const float* sentences = (const float*)d_in[3];
    const float* conv0_w   = (const float*)d_in[4];
    const float* conv0_b   = (const float*)d_in[5];
    const float* conv1_w   = (const float*)d_in[6];
    const float* conv1_b   = (const float*)d_in[7];
    const float* conv2_w   = (const float*)d_in[8];
    const float* conv2_b   = (const float*)d_in[9];
    const float* conv1d_w  = (const float*)d_in[10];
    const float* conv1d_b  = (const float*)d_in[11];
    const float* fc_w      = (const float*)d_in[12];
    const float* fc_b      = (const float*)d_in[13];
    float* out = (float*)d_out;
    float* ws = (float*)d_ws;

    // ---- flat workspace (float units) = R6 layout ----------------------------
    bf16_t* WT0    = (bf16_t*)(ws + 0);            // 1024x4096 bf16
    bf16_t* WT1    = (bf16_t*)(ws + 2097152);
    bf16_t* WT2    = (bf16_t*)(ws + 4194304);
    bf16_t* Vb     = (bf16_t*)(ws + 6291456);      // 4,194,304 bf16
    bf16_t* Wordsb = (bf16_t*)(ws + 8388608);      // 1,310,720 bf16
    bf16_t* C1b    = (bf16_t*)(ws + 9043968);      // 1,048,576 bf16
    bf16_t* Fb     = (bf16_t*)(ws + 9568256);      // 1,048,576 bf16
    bf16_t* Astack = (bf16_t*)(ws + 10092544);     // 1344x1024 bf16
    bf16_t* VCb    = (bf16_t*)(ws + 10780672);     // 1344x1024 bf16
    float*  CP0    = ws + 11468800;                // 4 x 1,048,576 f
    float*  CP1    = ws + 15663104;                // 16 x 262,144 f
    float*  CP2    = ws + 19857408;                // 32 x 65,536 f
    float*  CPcf   = ws + 21954560;                // 4 x 1,441,792 f
    float*  CPat   = ws + 27721728;                // 2 x 1,720,320 f
    float*  VN     = ws + 31162368;                // 1,344
    float*  GR     = ws + 31163712;                // 25,600
    float*  SA     = ws + 31189312;                // 86,016
    float*  SC     = ws + 31275328;                // 4,096
    float*  GV     = ws + 31279424;                // 65,536
    float*  GS     = ws + 31344960;                // 4,096 (ends 31,349,056)

    bf16_t* A2b = Astack + 1048576;   // rows 1024..1279
    bf16_t* A3b = Astack + 1310720;   // rows 1280..1343

    dim3 blk(256);

    // 1. prep: LDS-staged transposes (768 blocks) + casts (7424 blocks)
    prep_kernel<<<8192, blk, 0, stream>>>(
        conv0_w, conv1_w, conv2_w, WT0, WT1, WT2,
        video, Vb, words, Wordsb, conv1d_w, C1b, fc_w, Fb);

    // 2-3. conv0: M=1024 N=1024 K=4096, split-K x4 -> 1024 blocks (4/CU)
    mgemm_kernel<<<dim3(16,16,4), blk, 0, stream>>>(
        Vb, WT0, nullptr, CP0, 1024, 4096, 1024, -1, 0, 1048576);
    epilogueB_kernel<<<4096, blk, 0, stream>>>(CP0, 4, conv0_b, Astack, 1048576, 1024, 1);

    // 4-5. conv1: M=256 K=4096, split-K x16 -> 1024 blocks
    mgemm_kernel<<<dim3(4,16,16), blk, 0, stream>>>(
        Astack, WT1, nullptr, CP1, 1024, 4096, 256, -1, 0, 262144);
    epilogueB_kernel<<<1024, blk, 0, stream>>>(CP1, 16, conv1_b, A2b, 262144, 1024, 1);

    // 6-7. conv2: M=64 K=4096, split-K x32 -> 512 blocks
    mgemm_kernel<<<dim3(1,16,32), blk, 0, stream>>>(
        A2b, WT2, nullptr, CP2, 1024, 4096, 128, -1, 0, 65536);
    epilogueB_kernel<<<256, blk, 0, stream>>>(CP2, 32, conv2_b, A3b, 65536, 1024, 1);

    // 8-9. conv1d (M=1344) + fc (M=64) in ONE launch; split-K x4 -> 1408 blocks
    mgemm_kernel<<<dim3(22,16,4), blk, 0, stream>>>(
        Astack, C1b, Fb, CPcf, 1024, 1024, 256, 21, 1280, 1441792);
    epilogueCF_kernel<<<5632, blk, 0, stream>>>(CPcf, conv1d_b, fc_b, VCb, GV);

    // 10. attn GEMM (840 blocks) + rownorm (1344) + gram (6400) in ONE dispatch
    attn_ng_kernel<<<8584, blk, 0, stream>>>(
        Wordsb, VCb, CPat, VCb, VN, Wordsb, GR);

    // 11-13. tail
    sim_kernel<<<dim3(64,6), blk, 0, stream>>>(CPat, GR, VN, w_masks, SA);
    sg_kernel<<<1040, blk, 0, stream>>>(SA, SC, out, sentences, GV, GS);
    loss_kernel<<<1, blk, 0, stream>>>(SC, GS, out);
}